// Round 3
// baseline (217.086 us; speedup 1.0000x reference)
//
#include <hip/hip_runtime.h>
#include <math.h>

#define NT    256               // threads per block
#define CH    (NT * 4)          // floats per chunk (one float4 per thread)

// One block per 1024-float chunk of one row (m13-style: 1 float4/thread,
// 256-thread blocks, max TLP). Each block copies its chunk, syncs, then
// redundantly scans the row's windows and applies -inf only to banned
// positions inside its own chunk -> ordering is intra-block, one dispatch.
// Scalars (bsz/step/beam/n) are device-side (graph capture forbids host sync
// reads); R/S/V derived on-device from flat element counts.
__global__ void __launch_bounds__(NT)
ngram_fused_chunks(const int* __restrict__ tokens,
                   const float* __restrict__ lprobs,
                   float* __restrict__ out,
                   const int* __restrict__ bsz_p,
                   const int* __restrict__ step_p,
                   const int* __restrict__ beam_p,
                   const int* __restrict__ n_p,
                   long long tok_elems, long long lp_elems) {
    const int bsz  = *bsz_p;
    const int step = *step_p;
    const int beam = *beam_p;
    const int n    = *n_p;

    const int R = bsz * beam;
    const long long S = tok_elems / R;
    const long long V = lp_elems / R;
    const int cpr = (int)((V + CH - 1) / CH);          // chunks per row
    const long long total_chunks = (long long)R * cpr;

    const int tid = threadIdx.x;

    for (long long c = blockIdx.x; c < total_chunks; c += gridDim.x) {
        const int r = (int)(c / cpr);
        const int s = (int)(c - (long long)r * cpr);

        const long long base = (long long)r * V;
        const long long rend = base + V;
        const long long a    = (base + 3) & ~3LL;      // first 16B-aligned float
        const long long b    = rend & ~3LL;            // last aligned boundary
        const long long nv   = (b - a) >> 2;           // aligned float4 count

        // ---- copy phase: one float4 per thread ----
        const long long q = (long long)s * NT + tid;   // this thread's f4 index
        if (q < nv) {
            ((float4*)(out + a))[q] = ((const float4*)(lprobs + a))[q];
        }
        if (s == 0 && tid < (int)(a - base)) {         // head scalars (<4)
            out[base + tid] = lprobs[base + tid];
        }
        if (s == cpr - 1 && tid < (int)(rend - b)) {   // tail scalars (<4)
            out[b + tid] = lprobs[b + tid];
        }

        __syncthreads();

        // ---- ban phase: redundant scan, apply only inside own chunk ----
        long long clo = (s == 0) ? base : a + (long long)s * CH;
        long long chi = a + (long long)(s + 1) * CH;
        if (chi > rend || s == cpr - 1) chi = rend;

        const int num_windows = step - n + 2;
        const int last_start  = step - n + 2;
        const int L = n - 1;
        const int* __restrict__ trow = tokens + (long long)r * S;

        for (int j = tid; j < num_windows; j += NT) {
            bool m = true;
            for (int k = 0; k < L; ++k) {
                m &= (trow[j + k] == trow[last_start + k]);
            }
            if (m) {
                const long long pos = base + trow[j + n - 1];
                if (pos >= clo && pos < chi) out[pos] = -INFINITY;
            }
        }
        __syncthreads();   // isolate iterations if a block loops over >1 chunk
    }
}

extern "C" void kernel_launch(void* const* d_in, const int* in_sizes, int n_in,
                              void* d_out, int out_size, void* d_ws, size_t ws_size,
                              hipStream_t stream) {
    const int*   tokens = (const int*)d_in[0];
    const float* lprobs = (const float*)d_in[1];
    const int*   bsz_p  = (const int*)d_in[2];
    const int*   step_p = (const int*)d_in[3];
    const int*   beam_p = (const int*)d_in[4];
    const int*   n_p    = (const int*)d_in[5];
    float* out = (float*)d_out;

    // Expected shape: R=512 rows, V=50257 -> cpr=50 -> 25600 chunks.
    // Fixed grid + device-side stride loop keeps it correct for any R.
    const int blocks = 25600;
    ngram_fused_chunks<<<blocks, NT, 0, stream>>>(
        tokens, lprobs, out, bsz_p, step_p, beam_p, n_p,
        (long long)in_sizes[0], (long long)in_sizes[1]);
}

// Round 4
// 191.863 us; speedup vs baseline: 1.1315x; 1.1315x over previous
//
#include <hip/hip_runtime.h>
#include <math.h>

// Kernel 1: m13-style pure copy — one float4 per thread, 256-thread blocks,
// exact grid (no grid-stride loop), 32-bit indexing. Tail (out_size % 4)
// handled by the first threads of block 0 (tail is <4 elements).
__global__ void __launch_bounds__(256)
ngram_copy(const float4* __restrict__ in4, float4* __restrict__ out4,
           const float* __restrict__ in, float* __restrict__ out,
           int n4, int tail) {
    int i = blockIdx.x * 256 + threadIdx.x;
    if (i < n4) out4[i] = in4[i];
    if (blockIdx.x == 0 && threadIdx.x < tail) {
        int t = n4 * 4 + threadIdx.x;
        out[t] = in[t];
    }
}

// Kernel 2: ban scan + scatter (runs after copy on the same stream).
// One block per row (grid-stride for safety); threads stride the windows.
// Scalars are device-side (graph capture forbids host sync reads), so
// R/S/V are derived on-device from flat element counts.
__global__ void __launch_bounds__(256)
ngram_ban(const int* __restrict__ tokens, float* __restrict__ out,
          const int* __restrict__ bsz_p, const int* __restrict__ step_p,
          const int* __restrict__ beam_p, const int* __restrict__ n_p,
          long long tok_elems, long long lp_elems) {
    const int bsz  = *bsz_p;
    const int step = *step_p;
    const int beam = *beam_p;
    const int n    = *n_p;

    const int R = bsz * beam;
    const long long S = tok_elems / R;
    const long long V = lp_elems / R;
    const int num_windows = step - n + 2;
    const int last_start  = step - n + 2;
    const int L = n - 1;

    for (int r = blockIdx.x; r < R; r += gridDim.x) {
        const int* __restrict__ trow = tokens + (long long)r * S;
        for (int j = threadIdx.x; j < num_windows; j += blockDim.x) {
            bool m = true;
            for (int k = 0; k < L; ++k) {
                m &= (trow[j + k] == trow[last_start + k]);
            }
            if (m) {
                const int banned = trow[j + n - 1];
                out[(long long)r * V + banned] = -INFINITY;
            }
        }
    }
}

extern "C" void kernel_launch(void* const* d_in, const int* in_sizes, int n_in,
                              void* d_out, int out_size, void* d_ws, size_t ws_size,
                              hipStream_t stream) {
    const int*   tokens = (const int*)d_in[0];
    const float* lprobs = (const float*)d_in[1];
    const int*   bsz_p  = (const int*)d_in[2];
    const int*   step_p = (const int*)d_in[3];
    const int*   beam_p = (const int*)d_in[4];
    const int*   n_p    = (const int*)d_in[5];
    float* out = (float*)d_out;

    // 1) pure copy at max BW: exact grid, one float4/thread
    {
        const int n4   = out_size / 4;        // 6,432,896 for this shape
        const int tail = out_size - n4 * 4;   // 0 here
        const int blocks = (n4 + 255) / 256;
        ngram_copy<<<blocks, 256, 0, stream>>>(
            (const float4*)lprobs, (float4*)out, lprobs, out, n4, tail);
    }

    // 2) tiny ban scan + scatter (stream-ordered after the copy)
    {
        const int blocks = 512;   // one per row (R=512); loop covers mismatch
        ngram_ban<<<blocks, 256, 0, stream>>>(
            tokens, out, bsz_p, step_p, beam_p, n_p,
            (long long)in_sizes[0], (long long)in_sizes[1]);
    }
}